// Round 4
// baseline (84.472 us; speedup 1.0000x reference)
//
#include <hip/hip_runtime.h>
#include <math.h>

#define N 512
#define BATCH 256
#define KTOP 16
#define NLAYERS 45
#define NPAIRS 256

// alpha = atan(t)/pi + 0.5 via minimax odd poly (deg 11) + rcp range
// reduction. |err| ~1e-7 in alpha; output threshold is 1.2e-2.
__device__ __forceinline__ float fast_alpha(float t) {
    const float at  = __builtin_fabsf(t);
    const bool inv  = at > 1.0f;
    const float z   = inv ? __builtin_amdgcn_rcpf(at) : at;
    const float s   = z * z;
    float p = -0.0117212f;
    p = __builtin_fmaf(p, s,  0.05265332f);
    p = __builtin_fmaf(p, s, -0.11643287f);
    p = __builtin_fmaf(p, s,  0.19354346f);
    p = __builtin_fmaf(p, s, -0.33262347f);
    p = __builtin_fmaf(p, s,  0.99997726f);
    float r = z * p;
    r = inv ? (1.5707963267948966f - r) : r;
    r = (t < 0.0f) ? -r : r;
    return __builtin_fmaf(r, 0.3183098861837907f, 0.5f);
}

// One 512-thread block (8 waves) per batch element.
//
// Forward (verified in R3): element i on lane (i&63) of wave (i>>6), in a
//   register. j<64 -> intra-wave shfl_xor (39 layers); j in {64,128,256} ->
//   ping-pong LDS + barrier (6 layers). Alphas -> As[t][pair_ordinal].
//
// Backward v3 (DS-pipe diet): out row kk = row (511-kk) of the layer product;
//   propagate one-hot row vectors through layers in reverse (pair matrix is
//   symmetric -> same update form). 4 waves x 4 rows; each row on a 16-lane
//   group, lane h holds positions p = 32h..32h+31 in v[32] registers.
//   j < 32 (35 of 45 layers): in-register in-place pair update, ZERO DS ops.
//   j >= 32 (10 layers): 32 bpermutes/wave (vs 128/wave-equivalent before).
//   Alpha ordinals are consecutive per lane -> aligned float4 LDS loads.
__global__ __launch_bounds__(512, 1)
void difftopk_kernel(const float* __restrict__ x_in, float* __restrict__ out) {
    __shared__ float xs[2][N];
    __shared__ __align__(16) float As[NLAYERS][NPAIRS];

    const int b    = blockIdx.x;
    const int e    = threadIdx.x;   // element 0..511

    // ---------------- forward ----------------
    float o = x_in[(size_t)b * N + e];

    int t = 0, par = 0;
    #pragma unroll 1
    for (int s = 1; s <= 9; ++s) {
        const int k  = 1 << s;
        const bool kb = (e & k) == 0;
        #pragma unroll 1
        for (int lg = s - 1; lg >= 0; --lg, ++t) {
            const int j = 1 << lg;
            float p;
            if (lg >= 6) {              // cross-wave: LDS ping-pong
                xs[par][e] = o;
                __syncthreads();
                p = xs[par][e ^ j];
                par ^= 1;
            } else {                    // intra-wave
                p = __shfl_xor(o, j, 64);
            }
            const bool jb = (e & j) == 0;
            const float d = (kb == jb) ? (p - o) : (o - p);   // c - a
            const float alpha = fast_alpha(d * 10.0f);
            o = __builtin_fmaf(alpha, o - p, p);              // alpha*o+(1-alpha)*p
            if (jb) {
                const int ord = ((e >> (lg + 1)) << lg) | (e & (j - 1));
                As[t][ord] = alpha;
            }
        }
    }
    __syncthreads();   // publish all alphas

    // ---------------- backward (waves 0..3 only) ----------------
    const int w = e >> 6;
    if (w >= 4) return;

    const int lane = e & 63;
    const int g    = lane >> 4;        // row-group within wave
    const int h    = lane & 15;        // position-lane within group
    const int kk   = (w << 2) | g;     // output row 0..15
    const int r    = N - 1 - kk;       // one-hot position
    const int p0   = h << 5;           // 32 positions per lane

    float v[32];
    #pragma unroll
    for (int m = 0; m < 32; ++m) v[m] = (p0 + m == r) ? 1.0f : 0.0f;

    #pragma unroll 1
    for (int s = 9; s >= 1; --s) {
        const int base = (s * (s - 1)) >> 1;
        #pragma unroll 1
        for (int lg = 0; lg < s; ++lg) {
            const int tt = base + (s - 1 - lg);
            if (lg >= 5) {
                // cross-lane within 16-lane group: mask = j>>5 in {1,2,4,8}
                const int j    = 1 << lg;
                const int ordb = ((p0 >> (lg + 1)) << lg) | (p0 & (j - 1));
                float al[32];
                #pragma unroll
                for (int q = 0; q < 8; ++q) {
                    const float4 a = *(const float4*)&As[tt][ordb + (q << 2)];
                    al[4*q] = a.x; al[4*q+1] = a.y; al[4*q+2] = a.z; al[4*q+3] = a.w;
                }
                const int mask = j >> 5;
                #pragma unroll
                for (int m = 0; m < 32; ++m) {
                    const float pt = __shfl_xor(v[m], mask, 64);
                    v[m] = __builtin_fmaf(al[m], v[m] - pt, pt);
                }
            } else {
                // slot-local: 16 pairs among this lane's 32 positions, no DS for v
                float aa[16];
                #pragma unroll
                for (int q = 0; q < 4; ++q) {
                    const float4 a = *(const float4*)&As[tt][(h << 4) + (q << 2)];
                    aa[4*q] = a.x; aa[4*q+1] = a.y; aa[4*q+2] = a.z; aa[4*q+3] = a.w;
                }
                // pair i: lo = ((i>>lg)<<(lg+1)) | (i & (j-1)), hi = lo | j
                switch (lg) {
                case 4:
                    #pragma unroll
                    for (int i = 0; i < 16; ++i) {
                        const int lo = i, hi = i | 16;
                        const float x0 = v[lo], x1 = v[hi], a = aa[i];
                        v[lo] = __builtin_fmaf(a, x0 - x1, x1);
                        v[hi] = __builtin_fmaf(a, x1 - x0, x0);
                    }
                    break;
                case 3:
                    #pragma unroll
                    for (int i = 0; i < 16; ++i) {
                        const int lo = ((i >> 3) << 4) | (i & 7), hi = lo | 8;
                        const float x0 = v[lo], x1 = v[hi], a = aa[i];
                        v[lo] = __builtin_fmaf(a, x0 - x1, x1);
                        v[hi] = __builtin_fmaf(a, x1 - x0, x0);
                    }
                    break;
                case 2:
                    #pragma unroll
                    for (int i = 0; i < 16; ++i) {
                        const int lo = ((i >> 2) << 3) | (i & 3), hi = lo | 4;
                        const float x0 = v[lo], x1 = v[hi], a = aa[i];
                        v[lo] = __builtin_fmaf(a, x0 - x1, x1);
                        v[hi] = __builtin_fmaf(a, x1 - x0, x0);
                    }
                    break;
                case 1:
                    #pragma unroll
                    for (int i = 0; i < 16; ++i) {
                        const int lo = ((i >> 1) << 2) | (i & 1), hi = lo | 2;
                        const float x0 = v[lo], x1 = v[hi], a = aa[i];
                        v[lo] = __builtin_fmaf(a, x0 - x1, x1);
                        v[hi] = __builtin_fmaf(a, x1 - x0, x0);
                    }
                    break;
                default:
                    #pragma unroll
                    for (int i = 0; i < 16; ++i) {
                        const int lo = i << 1, hi = lo | 1;
                        const float x0 = v[lo], x1 = v[hi], a = aa[i];
                        v[lo] = __builtin_fmaf(a, x0 - x1, x1);
                        v[hi] = __builtin_fmaf(a, x1 - x0, x0);
                    }
                    break;
                }
            }
        }
    }

    // ---------------- write out[b, kk, p0..p0+31] ----------------
    float* dst = out + ((size_t)b * KTOP + kk) * N + p0;
    #pragma unroll
    for (int q = 0; q < 8; ++q)
        *(float4*)(dst + (q << 2)) = make_float4(v[4*q], v[4*q+1], v[4*q+2], v[4*q+3]);
}

extern "C" void kernel_launch(void* const* d_in, const int* in_sizes, int n_in,
                              void* d_out, int out_size, void* d_ws, size_t ws_size,
                              hipStream_t stream) {
    const float* x = (const float*)d_in[0];
    float* out = (float*)d_out;
    difftopk_kernel<<<dim3(BATCH), dim3(512), 0, stream>>>(x, out);
}

// Round 5
// 76.356 us; speedup vs baseline: 1.1063x; 1.1063x over previous
//
#include <hip/hip_runtime.h>
#include <math.h>

#define N 512
#define BATCH 256
#define KTOP 16
#define NLAYERS 45
#define NPAIRS 256

// alpha = atan(t)/pi + 0.5 via minimax odd poly (deg 11) + rcp range
// reduction. |err| ~1e-7 in alpha; output threshold is 1.2e-2.
__device__ __forceinline__ float fast_alpha(float t) {
    const float at  = __builtin_fabsf(t);
    const bool inv  = at > 1.0f;
    const float z   = inv ? __builtin_amdgcn_rcpf(at) : at;
    const float s   = z * z;
    float p = -0.0117212f;
    p = __builtin_fmaf(p, s,  0.05265332f);
    p = __builtin_fmaf(p, s, -0.11643287f);
    p = __builtin_fmaf(p, s,  0.19354346f);
    p = __builtin_fmaf(p, s, -0.33262347f);
    p = __builtin_fmaf(p, s,  0.99997726f);
    float r = z * p;
    r = inv ? (1.5707963267948966f - r) : r;
    r = (t < 0.0f) ? -r : r;
    return __builtin_fmaf(r, 0.3183098861837907f, 0.5f);
}

// One 512-thread block (8 waves) per batch element.  (R3 structure — best
// measured; R4's 32-slot variant regressed from latency exposure at 4 waves.)
//
// Forward: element i on lane (i&63) of wave (i>>6), in a register.
//   j<64 -> intra-wave shfl_xor (39 layers, no barrier); j in {64,128,256} ->
//   ping-pong LDS + 1 barrier (6 layers). Alphas -> As[t][pair_ordinal].
//
// Backward: out row kk = row (511-kk) of L45*...*L1*I; propagate one-hot row
//   vectors through layers in reverse (pair matrix symmetric -> same update
//   form). 8 waves x 2 rows/wave, element i at (lane=i>>3, slot=i&7):
//   j>=8 -> shfl_xor by j>>3; j<8 -> in-register slot swap. Alpha float4
//   loads shared by both rows. unroll 2 on the layer loop pipelines the
//   next layer's (v-independent) alpha ds_read_b128s under this layer's FMAs.
__global__ __launch_bounds__(512, 2)
void difftopk_kernel(const float* __restrict__ x_in, float* __restrict__ out) {
    __shared__ float xs[2][N];
    __shared__ __align__(16) float As[NLAYERS][NPAIRS];

    const int b    = blockIdx.x;
    const int e    = threadIdx.x;   // element 0..511
    const int lane = e & 63;

    // ---------------- forward ----------------
    float o = x_in[(size_t)b * N + e];

    int t = 0, par = 0;
    #pragma unroll 1
    for (int s = 1; s <= 9; ++s) {
        const int k  = 1 << s;
        const bool kb = (e & k) == 0;
        #pragma unroll 1
        for (int lg = s - 1; lg >= 0; --lg, ++t) {
            const int j = 1 << lg;
            float p;
            if (lg >= 6) {              // cross-wave: LDS ping-pong
                xs[par][e] = o;
                __syncthreads();
                p = xs[par][e ^ j];
                par ^= 1;
            } else {                    // intra-wave
                p = __shfl_xor(o, j, 64);
            }
            const bool jb = (e & j) == 0;
            const float d = (kb == jb) ? (p - o) : (o - p);   // c - a
            const float alpha = fast_alpha(d * 10.0f);
            o = __builtin_fmaf(alpha, o - p, p);              // alpha*o+(1-alpha)*p
            if (jb) {
                const int ord = ((e >> (lg + 1)) << lg) | (e & (j - 1));
                As[t][ord] = alpha;
            }
        }
    }
    __syncthreads();   // publish all alphas

    // ---------------- backward ----------------
    const int wave  = e >> 6;          // 0..7 -> rows kk = wave, wave+8
    const int lane8 = lane << 3;
    const int r0 = N - 1 - wave;
    const int r1 = N - 1 - (wave + 8);

    float v0[8], v1[8];
    #pragma unroll
    for (int m = 0; m < 8; ++m) {
        v0[m] = (lane8 + m == r0) ? 1.0f : 0.0f;
        v1[m] = (lane8 + m == r1) ? 1.0f : 0.0f;
    }

    #pragma unroll 1
    for (int s = 9; s >= 1; --s) {
        const int base = (s * (s - 1)) >> 1;
        #pragma unroll 2
        for (int lg = 0; lg < s; ++lg) {
            const int tt = base + (s - 1 - lg);
            if (lg >= 3) {
                const int j    = 1 << lg;
                const int ordb = ((lane8 >> (lg + 1)) << lg) | (lane8 & (j - 1));
                const float4 a0 = *(const float4*)&As[tt][ordb];
                const float4 a1 = *(const float4*)&As[tt][ordb + 4];
                const float al[8] = {a0.x, a0.y, a0.z, a0.w, a1.x, a1.y, a1.z, a1.w};
                const int lm = j >> 3;
                #pragma unroll
                for (int m = 0; m < 8; ++m) {
                    const float p0 = __shfl_xor(v0[m], lm, 64);
                    const float p1 = __shfl_xor(v1[m], lm, 64);
                    v0[m] = __builtin_fmaf(al[m], v0[m] - p0, p0);
                    v1[m] = __builtin_fmaf(al[m], v1[m] - p1, p1);
                }
            } else {
                const float4 a = *(const float4*)&As[tt][lane << 2];
                const float aa[4] = {a.x, a.y, a.z, a.w};
                float n0[8], n1[8];
                if (lg == 2) {
                    #pragma unroll
                    for (int m = 0; m < 8; ++m) {
                        const float al = aa[m & 3];
                        n0[m] = __builtin_fmaf(al, v0[m] - v0[m ^ 4], v0[m ^ 4]);
                        n1[m] = __builtin_fmaf(al, v1[m] - v1[m ^ 4], v1[m ^ 4]);
                    }
                } else if (lg == 1) {
                    #pragma unroll
                    for (int m = 0; m < 8; ++m) {
                        const float al = aa[((m >> 2) << 1) | (m & 1)];
                        n0[m] = __builtin_fmaf(al, v0[m] - v0[m ^ 2], v0[m ^ 2]);
                        n1[m] = __builtin_fmaf(al, v1[m] - v1[m ^ 2], v1[m ^ 2]);
                    }
                } else {
                    #pragma unroll
                    for (int m = 0; m < 8; ++m) {
                        const float al = aa[m >> 1];
                        n0[m] = __builtin_fmaf(al, v0[m] - v0[m ^ 1], v0[m ^ 1]);
                        n1[m] = __builtin_fmaf(al, v1[m] - v1[m ^ 1], v1[m ^ 1]);
                    }
                }
                #pragma unroll
                for (int m = 0; m < 8; ++m) { v0[m] = n0[m]; v1[m] = n1[m]; }
            }
        }
    }

    // ---------------- write out ----------------
    float4* dst0 = (float4*)(out + ((size_t)b * KTOP + wave) * N + lane8);
    dst0[0] = make_float4(v0[0], v0[1], v0[2], v0[3]);
    dst0[1] = make_float4(v0[4], v0[5], v0[6], v0[7]);
    float4* dst1 = (float4*)(out + ((size_t)b * KTOP + wave + 8) * N + lane8);
    dst1[0] = make_float4(v1[0], v1[1], v1[2], v1[3]);
    dst1[1] = make_float4(v1[4], v1[5], v1[6], v1[7]);
}

extern "C" void kernel_launch(void* const* d_in, const int* in_sizes, int n_in,
                              void* d_out, int out_size, void* d_ws, size_t ws_size,
                              hipStream_t stream) {
    const float* x = (const float*)d_in[0];
    float* out = (float*)d_out;
    difftopk_kernel<<<dim3(BATCH), dim3(512), 0, stream>>>(x, out);
}

// Round 6
// 65.709 us; speedup vs baseline: 1.2855x; 1.1620x over previous
//
#include <hip/hip_runtime.h>
#include <math.h>

#define N 512
#define BATCH 256
#define KTOP 16
#define NLAYERS 45
#define NPAIRS 256

// Cross-lane xor via DPP (VALU pipe, NOT the DS pipe):
//   xor1 = quad_perm[1,0,3,2] = 0xB1; xor2 = quad_perm[2,3,0,1] = 0x4E;
//   xor8 = row_ror:8 = 0x128 (rotate by half a 16-lane row == xor 8,
//   direction-immune). xor4/16/32 stay on __shfl_xor (DS).
template<int CTRL>
__device__ __forceinline__ float dpp_xor(float x) {
    return __int_as_float(
        __builtin_amdgcn_mov_dpp(__float_as_int(x), CTRL, 0xF, 0xF, true));
}

// alpha = atan(t)/pi + 0.5 via minimax odd poly (deg 11) + rcp range
// reduction. |err| ~1e-7 in alpha; output threshold is 1.2e-2.
__device__ __forceinline__ float fast_alpha(float t) {
    const float at  = __builtin_fabsf(t);
    const bool inv  = at > 1.0f;
    const float z   = inv ? __builtin_amdgcn_rcpf(at) : at;
    const float s   = z * z;
    float p = -0.0117212f;
    p = __builtin_fmaf(p, s,  0.05265332f);
    p = __builtin_fmaf(p, s, -0.11643287f);
    p = __builtin_fmaf(p, s,  0.19354346f);
    p = __builtin_fmaf(p, s, -0.33262347f);
    p = __builtin_fmaf(p, s,  0.99997726f);
    float r = z * p;
    r = inv ? (1.5707963267948966f - r) : r;
    r = (t < 0.0f) ? -r : r;
    return __builtin_fmaf(r, 0.3183098861837907f, 0.5f);
}

// One 512-thread block (8 waves) per batch element.
//
// Forward: element i on lane (i&63) of wave (i>>6), in a register.
//   j in {1,2,8} -> DPP (23 layers, VALU); j in {4,16,32} -> shfl (16
//   layers, DS); j in {64,128,256} -> ping-pong LDS + barrier (6 layers).
//   Alphas -> As[t][pair_ordinal]. Fully unrolled (compile-time lg).
//
// Backward: out row kk = row (511-kk) of L45*...*L1*I; propagate one-hot row
//   vectors through layers in reverse (pair matrix symmetric -> same update
//   form). 8 waves x 2 rows/wave, element i at (lane=i>>3, slot=i&7).
//   j>=8: lane-xor lm=j>>3; lm in {1,2,8} -> DPP (14 of 21 layers),
//   lm in {4,16,32} -> shfl. j<8 -> in-register slot swap. Alpha float4
//   loads shared by both rows. Fully unrolled so the scheduler hoists
//   alpha ds_read_b128s across layers (R5's unroll-2 win, generalized).
__global__ __launch_bounds__(512, 2)
void difftopk_kernel(const float* __restrict__ x_in, float* __restrict__ out) {
    __shared__ float xs[2][N];
    __shared__ __align__(16) float As[NLAYERS][NPAIRS];

    const int b    = blockIdx.x;
    const int e    = threadIdx.x;   // element 0..511
    const int lane = e & 63;

    // ---------------- forward ----------------
    float o = x_in[(size_t)b * N + e];

    int t = 0, par = 0;
    #pragma unroll
    for (int s = 1; s <= 9; ++s) {
        const int k  = 1 << s;
        const bool kb = (e & k) == 0;
        #pragma unroll
        for (int lg = s - 1; lg >= 0; --lg, ++t) {
            const int j = 1 << lg;
            float p;
            if (lg >= 6) {              // cross-wave: LDS ping-pong
                xs[par][e] = o;
                __syncthreads();
                p = xs[par][e ^ j];
                par ^= 1;
            } else if (lg == 0) {
                p = dpp_xor<0xB1>(o);
            } else if (lg == 1) {
                p = dpp_xor<0x4E>(o);
            } else if (lg == 3) {
                p = dpp_xor<0x128>(o);
            } else {                    // j in {4,16,32}
                p = __shfl_xor(o, j, 64);
            }
            const bool jb = (e & j) == 0;
            const float d = (kb == jb) ? (p - o) : (o - p);   // c - a
            const float alpha = fast_alpha(d * 10.0f);
            o = __builtin_fmaf(alpha, o - p, p);              // alpha*o+(1-alpha)*p
            if (jb) {
                const int ord = ((e >> (lg + 1)) << lg) | (e & (j - 1));
                As[t][ord] = alpha;
            }
        }
    }
    __syncthreads();   // publish all alphas

    // ---------------- backward ----------------
    const int wave  = e >> 6;          // 0..7 -> rows kk = wave, wave+8
    const int lane8 = lane << 3;
    const int r0 = N - 1 - wave;
    const int r1 = N - 1 - (wave + 8);

    float v0[8], v1[8];
    #pragma unroll
    for (int m = 0; m < 8; ++m) {
        v0[m] = (lane8 + m == r0) ? 1.0f : 0.0f;
        v1[m] = (lane8 + m == r1) ? 1.0f : 0.0f;
    }

    #pragma unroll
    for (int s = 9; s >= 1; --s) {
        const int base = (s * (s - 1)) >> 1;
        #pragma unroll
        for (int lg = 0; lg < s; ++lg) {
            const int tt = base + (s - 1 - lg);
            if (lg >= 3) {
                const int j    = 1 << lg;
                const int ordb = ((lane8 >> (lg + 1)) << lg) | (lane8 & (j - 1));
                const float4 a0 = *(const float4*)&As[tt][ordb];
                const float4 a1 = *(const float4*)&As[tt][ordb + 4];
                const float al[8] = {a0.x, a0.y, a0.z, a0.w, a1.x, a1.y, a1.z, a1.w};
                #pragma unroll
                for (int m = 0; m < 8; ++m) {
                    float p0, p1;
                    if (lg == 3)      { p0 = dpp_xor<0xB1>(v0[m]);  p1 = dpp_xor<0xB1>(v1[m]);  }
                    else if (lg == 4) { p0 = dpp_xor<0x4E>(v0[m]);  p1 = dpp_xor<0x4E>(v1[m]);  }
                    else if (lg == 6) { p0 = dpp_xor<0x128>(v0[m]); p1 = dpp_xor<0x128>(v1[m]); }
                    else              { p0 = __shfl_xor(v0[m], j >> 3, 64);
                                        p1 = __shfl_xor(v1[m], j >> 3, 64); }
                    v0[m] = __builtin_fmaf(al[m], v0[m] - p0, p0);
                    v1[m] = __builtin_fmaf(al[m], v1[m] - p1, p1);
                }
            } else {
                const float4 a = *(const float4*)&As[tt][lane << 2];
                const float aa[4] = {a.x, a.y, a.z, a.w};
                float n0[8], n1[8];
                if (lg == 2) {
                    #pragma unroll
                    for (int m = 0; m < 8; ++m) {
                        const float al = aa[m & 3];
                        n0[m] = __builtin_fmaf(al, v0[m] - v0[m ^ 4], v0[m ^ 4]);
                        n1[m] = __builtin_fmaf(al, v1[m] - v1[m ^ 4], v1[m ^ 4]);
                    }
                } else if (lg == 1) {
                    #pragma unroll
                    for (int m = 0; m < 8; ++m) {
                        const float al = aa[((m >> 2) << 1) | (m & 1)];
                        n0[m] = __builtin_fmaf(al, v0[m] - v0[m ^ 2], v0[m ^ 2]);
                        n1[m] = __builtin_fmaf(al, v1[m] - v1[m ^ 2], v1[m ^ 2]);
                    }
                } else {
                    #pragma unroll
                    for (int m = 0; m < 8; ++m) {
                        const float al = aa[m >> 1];
                        n0[m] = __builtin_fmaf(al, v0[m] - v0[m ^ 1], v0[m ^ 1]);
                        n1[m] = __builtin_fmaf(al, v1[m] - v1[m ^ 1], v1[m ^ 1]);
                    }
                }
                #pragma unroll
                for (int m = 0; m < 8; ++m) { v0[m] = n0[m]; v1[m] = n1[m]; }
            }
        }
    }

    // ---------------- write out ----------------
    float4* dst0 = (float4*)(out + ((size_t)b * KTOP + wave) * N + lane8);
    dst0[0] = make_float4(v0[0], v0[1], v0[2], v0[3]);
    dst0[1] = make_float4(v0[4], v0[5], v0[6], v0[7]);
    float4* dst1 = (float4*)(out + ((size_t)b * KTOP + wave + 8) * N + lane8);
    dst1[0] = make_float4(v1[0], v1[1], v1[2], v1[3]);
    dst1[1] = make_float4(v1[4], v1[5], v1[6], v1[7]);
}

extern "C" void kernel_launch(void* const* d_in, const int* in_sizes, int n_in,
                              void* d_out, int out_size, void* d_ws, size_t ws_size,
                              hipStream_t stream) {
    const float* x = (const float*)d_in[0];
    float* out = (float*)d_out;
    difftopk_kernel<<<dim3(BATCH), dim3(512), 0, stream>>>(x, out);
}

// Round 7
// 65.702 us; speedup vs baseline: 1.2857x; 1.0001x over previous
//
#include <hip/hip_runtime.h>
#include <math.h>

#define N 512
#define BATCH 256
#define KTOP 16
#define NLAYERS 45
#define NPAIRS 256

// Cross-lane xor via DPP (VALU pipe, NOT the DS pipe):
//   xor1 = quad_perm[1,0,3,2] = 0xB1; xor2 = quad_perm[2,3,0,1] = 0x4E;
//   xor8 = row_ror:8 = 0x128 (rotate by half a 16-lane row == xor 8,
//   direction-immune). xor4/16/32 stay on __shfl_xor (DS).
template<int CTRL>
__device__ __forceinline__ float dpp_xor(float x) {
    return __int_as_float(
        __builtin_amdgcn_mov_dpp(__float_as_int(x), CTRL, 0xF, 0xF, true));
}

// alpha = atan(t)/pi + 0.5 via minimax odd poly (deg 11) + rcp range
// reduction. |err| ~1e-7 in alpha; output threshold is 1.2e-2.
__device__ __forceinline__ float fast_alpha(float t) {
    const float at  = __builtin_fabsf(t);
    const bool inv  = at > 1.0f;
    const float z   = inv ? __builtin_amdgcn_rcpf(at) : at;
    const float s   = z * z;
    float p = -0.0117212f;
    p = __builtin_fmaf(p, s,  0.05265332f);
    p = __builtin_fmaf(p, s, -0.11643287f);
    p = __builtin_fmaf(p, s,  0.19354346f);
    p = __builtin_fmaf(p, s, -0.33262347f);
    p = __builtin_fmaf(p, s,  0.99997726f);
    float r = z * p;
    r = inv ? (1.5707963267948966f - r) : r;
    r = (t < 0.0f) ? -r : r;
    return __builtin_fmaf(r, 0.3183098861837907f, 0.5f);
}

// One 1024-thread block (16 waves = 4 waves/SIMD) per batch element.
//
// Forward (waves 0-7): element i on lane (i&63) of wave (i>>6), in a
//   register. j in {1,2,8} -> DPP; j in {4,16,32} -> shfl; j in
//   {64,128,256} -> ping-pong LDS + barrier (6 layers). Alphas ->
//   As[t][pair_ordinal]. Waves 8-15 execute the matching 7 barriers.
//
// Backward (all 16 waves): out row kk = row (511-kk) of L45*...*L1*I;
//   propagate one-hot row vectors in reverse (pair matrix symmetric -> same
//   update form). ONE row per wave, element i at (lane=i>>3, slot=i&7).
//   j>=8: lane-xor lm=j>>3: lm in {1,2,8} -> DPP, {4,16,32} -> shfl.
//   j<8 -> in-register slot pairs (3 VALU / 2 positions). Fully unrolled.
__global__ __launch_bounds__(1024, 1)
void difftopk_kernel(const float* __restrict__ x_in, float* __restrict__ out) {
    __shared__ float xs[2][N];
    __shared__ __align__(16) float As[NLAYERS][NPAIRS];

    const int b    = blockIdx.x;
    const int tid  = threadIdx.x;
    const int lane = tid & 63;

    // ---------------- forward (waves 0-7) ----------------
    if (tid < N) {
        const int e = tid;
        float o = x_in[(size_t)b * N + e];

        int t = 0, par = 0;
        #pragma unroll
        for (int s = 1; s <= 9; ++s) {
            const int k  = 1 << s;
            const bool kb = (e & k) == 0;
            #pragma unroll
            for (int lg = s - 1; lg >= 0; --lg, ++t) {
                const int j = 1 << lg;
                float p;
                if (lg >= 6) {              // cross-wave: LDS ping-pong
                    xs[par][e] = o;
                    __syncthreads();
                    p = xs[par][e ^ j];
                    par ^= 1;
                } else if (lg == 0) {
                    p = dpp_xor<0xB1>(o);
                } else if (lg == 1) {
                    p = dpp_xor<0x4E>(o);
                } else if (lg == 3) {
                    p = dpp_xor<0x128>(o);
                } else {                    // j in {4,16,32}
                    p = __shfl_xor(o, j, 64);
                }
                const bool jb = (e & j) == 0;
                const float d = (kb == jb) ? (p - o) : (o - p);   // c - a
                const float alpha = fast_alpha(d * 10.0f);
                o = __builtin_fmaf(alpha, o - p, p);
                if (jb) {
                    const int ord = ((e >> (lg + 1)) << lg) | (e & (j - 1));
                    As[t][ord] = alpha;
                }
            }
        }
        __syncthreads();   // publish all alphas (barrier #7)
    } else {
        // waves 8-15: match forward's 7 barriers (6 ping-pong + 1 publish)
        #pragma unroll 1
        for (int i = 0; i < 7; ++i) __syncthreads();
    }

    // ---------------- backward (all 16 waves, 1 row each) ----------------
    const int wave  = tid >> 6;        // 0..15 -> output row kk = wave
    const int lane8 = lane << 3;
    const int r     = N - 1 - wave;

    float v[8];
    #pragma unroll
    for (int m = 0; m < 8; ++m) v[m] = (lane8 + m == r) ? 1.0f : 0.0f;

    #pragma unroll
    for (int s = 9; s >= 1; --s) {
        const int base = (s * (s - 1)) >> 1;
        #pragma unroll
        for (int lg = 0; lg < s; ++lg) {
            const int tt = base + (s - 1 - lg);
            if (lg >= 3) {
                const int j    = 1 << lg;
                const int ordb = ((lane8 >> (lg + 1)) << lg) | (lane8 & (j - 1));
                const float4 a0 = *(const float4*)&As[tt][ordb];
                const float4 a1 = *(const float4*)&As[tt][ordb + 4];
                const float al[8] = {a0.x, a0.y, a0.z, a0.w, a1.x, a1.y, a1.z, a1.w};
                #pragma unroll
                for (int m = 0; m < 8; ++m) {
                    float p;
                    if (lg == 3)      p = dpp_xor<0xB1>(v[m]);
                    else if (lg == 4) p = dpp_xor<0x4E>(v[m]);
                    else if (lg == 6) p = dpp_xor<0x128>(v[m]);
                    else              p = __shfl_xor(v[m], j >> 3, 64);
                    v[m] = __builtin_fmaf(al[m], v[m] - p, p);
                }
            } else {
                const float4 a = *(const float4*)&As[tt][lane << 2];
                const float aa[4] = {a.x, a.y, a.z, a.w};
                if (lg == 2) {
                    #pragma unroll
                    for (int i = 0; i < 4; ++i) {
                        const float x0 = v[i], x1 = v[i + 4], d = x0 - x1;
                        v[i]     = __builtin_fmaf(aa[i],  d, x1);
                        v[i + 4] = __builtin_fmaf(aa[i], -d, x0);
                    }
                } else if (lg == 1) {
                    #pragma unroll
                    for (int i = 0; i < 4; ++i) {
                        const int lo = (((i >> 1) << 2) | (i & 1));
                        const float x0 = v[lo], x1 = v[lo + 2], d = x0 - x1;
                        v[lo]     = __builtin_fmaf(aa[i],  d, x1);
                        v[lo + 2] = __builtin_fmaf(aa[i], -d, x0);
                    }
                } else {
                    #pragma unroll
                    for (int i = 0; i < 4; ++i) {
                        const int lo = i << 1;
                        const float x0 = v[lo], x1 = v[lo + 1], d = x0 - x1;
                        v[lo]     = __builtin_fmaf(aa[i],  d, x1);
                        v[lo + 1] = __builtin_fmaf(aa[i], -d, x0);
                    }
                }
            }
        }
    }

    // ---------------- write out[b, wave, :] ----------------
    float4* dst = (float4*)(out + ((size_t)b * KTOP + wave) * N + lane8);
    dst[0] = make_float4(v[0], v[1], v[2], v[3]);
    dst[1] = make_float4(v[4], v[5], v[6], v[7]);
}

extern "C" void kernel_launch(void* const* d_in, const int* in_sizes, int n_in,
                              void* d_out, int out_size, void* d_ws, size_t ws_size,
                              hipStream_t stream) {
    const float* x = (const float*)d_in[0];
    float* out = (float*)d_out;
    difftopk_kernel<<<dim3(BATCH), dim3(1024), 0, stream>>>(x, out);
}